// Round 2
// baseline (196.359 us; speedup 1.0000x reference)
//
#include <hip/hip_runtime.h>

#define T_SEQ 2048
#define DHEAD 128
#define NBH 16
#define SCALE 0.08838834764831845f

typedef unsigned short u16;
typedef unsigned int u32;
typedef u16 u16x4 __attribute__((ext_vector_type(4)));
typedef u16 u16x8 __attribute__((ext_vector_type(8)));
typedef u32 u32x2 __attribute__((ext_vector_type(2)));
typedef short s16x4 __attribute__((ext_vector_type(4)));
typedef __bf16 bf16x8 __attribute__((ext_vector_type(8)));
typedef float f32x4 __attribute__((ext_vector_type(4)));

__device__ __forceinline__ u16 f2bfu(float x) {
  union { float f; unsigned u; } c; c.f = x;
  unsigned u = c.u;
  u = u + 0x7FFFu + ((u >> 16) & 1u);   // RNE
  return (u16)(u >> 16);
}

__device__ __forceinline__ u32 packbf2(float lo, float hi) {
  return (u32)f2bfu(lo) | ((u32)f2bfu(hi) << 16);
}

__device__ __forceinline__ bf16x8 ldsFrag(const u16* p) {
  u16x8 t = *(const u16x8*)p;
  return __builtin_bit_cast(bf16x8, t);
}

__device__ __forceinline__ f32x4 mfma16x16x16bf16(s16x4 a, s16x4 b, f32x4 c) {
#if __has_builtin(__builtin_amdgcn_mfma_f32_16x16x16bf16_1k)
  return __builtin_amdgcn_mfma_f32_16x16x16bf16_1k(a, b, c, 0, 0, 0);
#else
  asm("v_mfma_f32_16x16x16_bf16 %0, %1, %2, %0" : "+v"(c) : "v"(a), "v"(b));
  return c;
#endif
}

__device__ __forceinline__ void gld_lds16(const void* g, void* l) {
  __builtin_amdgcn_global_load_lds(
      (__attribute__((address_space(1))) const unsigned int*)g,
      (__attribute__((address_space(3))) unsigned int*)l, 16, 0, 0);
}

// ---------------------------------------------------------------------------
// Gate scan: fc=cumsum(logsigmoid(f)); a=i-fc; c=cummax(a).
// ---------------------------------------------------------------------------
__global__ __launch_bounds__(1024) void gate_scan_kernel(
    const float* __restrict__ ig, const float* __restrict__ fg,
    float* __restrict__ a_out, float* __restrict__ c_out,
    float* __restrict__ fc_out)
{
  const int bh = blockIdx.x, tid = threadIdx.x;
  const int w = tid >> 6, lane = tid & 63;
  const int base = bh * T_SEQ + tid * 2;
  __shared__ float wsum[16];
  __shared__ float wmax[16];

  const float x0 = fg[base], x1 = fg[base + 1];
  const float ls0 = fminf(x0, 0.f) - log1pf(expf(-fabsf(x0)));
  const float ls1 = fminf(x1, 0.f) - log1pf(expf(-fabsf(x1)));
  const float s = ls0 + ls1;

  float sc = s;
#pragma unroll
  for (int off = 1; off < 64; off <<= 1) {
    const float t = __shfl_up(sc, off, 64);
    if (lane >= off) sc += t;
  }
  if (lane == 63) wsum[w] = sc;
  __syncthreads();
  float wo = 0.f;
#pragma unroll
  for (int i = 0; i < 15; ++i) if (i < w) wo += wsum[i];
  const float excl = wo + (sc - s);
  const float fc0 = excl + ls0;
  const float fc1 = excl + ls0 + ls1;
  fc_out[base] = fc0; fc_out[base + 1] = fc1;
  const float a0 = ig[base] - fc0;
  const float a1 = ig[base + 1] - fc1;
  a_out[base] = a0; a_out[base + 1] = a1;

  const float m = fmaxf(a0, a1);
  float mc = m;
#pragma unroll
  for (int off = 1; off < 64; off <<= 1) {
    const float t = __shfl_up(mc, off, 64);
    if (lane >= off) mc = fmaxf(mc, t);
  }
  if (lane == 63) wmax[w] = mc;
  __syncthreads();
  float wmo = -INFINITY;
#pragma unroll
  for (int i = 0; i < 15; ++i) if (i < w) wmo = fmaxf(wmo, wmax[i]);
  const float prev = __shfl_up(mc, 1, 64);
  float exclm = (lane > 0) ? prev : -INFINITY;
  exclm = fmaxf(exclm, wmo);
  c_out[base] = fmaxf(exclm, a0);
  c_out[base + 1] = fmaxf(exclm, m);
}

// ---------------------------------------------------------------------------
// Fused pre-pass: per (bh, 64-key tile):
//   K_hat = K * exp(a[s]-c_tile_end(s)) fp32->bf16   (direct)
//   V fp32 [key][n] -> bf16 transposed Vt [n][key]   (LDS transpose)
// ---------------------------------------------------------------------------
__global__ __launch_bounds__(256) void cvt_kv_kernel(
    const float* __restrict__ kk, const float* __restrict__ v,
    const float* __restrict__ ag, const float* __restrict__ cg,
    u16* __restrict__ kbf, u16* __restrict__ vt)
{
  const int bh = blockIdx.y, kt = blockIdx.x, tid = threadIdx.x;
  // ---- K part ----
  {
    const int r = tid >> 2;                 // 0..63
    const int c0 = (tid & 3) * 32;
    const int row = kt * 64 + r;
    const float sc = __expf(ag[bh * T_SEQ + row] - cg[bh * T_SEQ + (row | 63)]);
    const float* sp = kk + ((size_t)bh * T_SEQ + row) * DHEAD + c0;
    u16* dp = kbf + ((size_t)bh * T_SEQ + row) * DHEAD + c0;
#pragma unroll
    for (int j = 0; j < 8; ++j) {
      const float4 x = *(const float4*)(sp + j * 4);
      u16x4 pq;
      pq[0] = f2bfu(x.x * sc); pq[1] = f2bfu(x.y * sc);
      pq[2] = f2bfu(x.z * sc); pq[3] = f2bfu(x.w * sc);
      *(u16x4*)(dp + j * 4) = pq;
    }
  }
  // ---- V transpose part ----
  __shared__ __align__(16) u16 L[128 * 72];
  const int n0 = (tid & 31) * 4, k0 = (tid >> 5) * 8;
  const float* vp = v + ((size_t)bh * T_SEQ + kt * 64 + k0) * DHEAD + n0;
  u16 tv[4][8];
#pragma unroll
  for (int rr = 0; rr < 8; ++rr) {
    const float4 x = *(const float4*)(vp + rr * DHEAD);
    tv[0][rr] = f2bfu(x.x); tv[1][rr] = f2bfu(x.y);
    tv[2][rr] = f2bfu(x.z); tv[3][rr] = f2bfu(x.w);
  }
#pragma unroll
  for (int j = 0; j < 4; ++j) {
    u16x8 pq;
#pragma unroll
    for (int rr = 0; rr < 8; ++rr) pq[rr] = tv[j][rr];
    *(u16x8*)(&L[(n0 + j) * 72 + k0]) = pq;
  }
  __syncthreads();
  const int row = tid >> 1, s0 = (tid & 1) * 32;
  u16* op = vt + ((size_t)bh * DHEAD + row) * T_SEQ + kt * 64 + s0;
#pragma unroll
  for (int i = 0; i < 4; ++i)
    *(u16x8*)(op + i * 8) = *(const u16x8*)(&L[row * 72 + s0 + i * 8]);
}

// ---------------------------------------------------------------------------
// Main flash mLSTM.  256 blocks x 1024 thr (16 waves = 4/SIMD).
// UNIFORM 17-iteration schedule, 2 stages per iteration:
//   block (bh,p) runs tile A=31-p then tile B=p; ceil(nA/2)+ceil(nB/2)==17.
// Wave = kg(4) x sg(2) x rh(2): 16 keys x 32 qrows of stage 2g+sg.
//   -> each LDS K/V fragment read feeds 2 MFMAs (half the LDS traffic of
//      the 16-row variant), 17 barriers instead of 33.
// 4 stage-slots of 32KB (K16+V16), double-buffered as pairs; epilogue osh
// overlays the dead pair; Q for tile B prefetched before epilogue A.
// ---------------------------------------------------------------------------
template <bool FAST>
__global__ __launch_bounds__(1024, 4) void mlstm_fwd_kernel(
    const float* __restrict__ qg, const float* __restrict__ kxg,
    const float* __restrict__ vg,
    const u16* __restrict__ kbf, const u16* __restrict__ vtbf,
    const float* __restrict__ ag, const float* __restrict__ cg,
    const float* __restrict__ fcg, float* __restrict__ out)
{
  const int bx = (int)blockIdx.x;
  const int bh = bx & 15, p = bx >> 4;
  const int tid = (int)threadIdx.x;
  const int w = tid >> 6, lane = tid & 63;
  const int quad = lane >> 4, l16 = lane & 15;
  const int kg = w & 3, sg = (w >> 2) & 1, rh = w >> 3;

  const int qtA = 31 - p, qtB = p;

  // LDS: 4 stage-slots x 32KB @0 (K 16K + V 16K each);
  //      rsh 8x64 f32 @131072; ish 64 f32 @133120; osh overlays a slot-pair.
  __shared__ __align__(16) unsigned char SM[133376];
  float* rsh = (float*)(SM + 131072);
  float* ish = (float*)(SM + 133120);

  const size_t hoff = (size_t)bh * T_SEQ * DHEAD;
  const int goff = bh * T_SEQ;

  // Q -> B-frags qf[nt*4+kc]: B[k=quad*8+j][n=l16], row = qt*64+rh*32+nt*16+l16
  bf16x8 qf[8];
  auto loadQ = [&](int lqt) {
    const float* qp = qg + hoff + (size_t)(lqt * 64 + rh * 32 + l16) * DHEAD + quad * 8;
#pragma unroll
    for (int nt = 0; nt < 2; ++nt)
#pragma unroll
      for (int kc = 0; kc < 4; ++kc) {
        const float4 x0 = *(const float4*)(qp + nt * 16 * DHEAD + kc * 32);
        const float4 x1 = *(const float4*)(qp + nt * 16 * DHEAD + kc * 32 + 4);
        u16x8 t;
        t[0] = f2bfu(x0.x); t[1] = f2bfu(x0.y); t[2] = f2bfu(x0.z); t[3] = f2bfu(x0.w);
        t[4] = f2bfu(x1.x); t[5] = f2bfu(x1.y); t[6] = f2bfu(x1.z); t[7] = f2bfu(x1.w);
        qf[nt * 4 + kc] = __builtin_bit_cast(bf16x8, t);
      }
  };

  f32x4 oa[8][2];                        // O^T partial: 8 vd-tiles x 2 row-tiles
  float rs0, rs1;
  auto zeroAcc = [&]() {
#pragma unroll
    for (int mt = 0; mt < 8; ++mt) {
      oa[mt][0] = (f32x4){0.f, 0.f, 0.f, 0.f};
      oa[mt][1] = (f32x4){0.f, 0.f, 0.f, 0.f};
    }
    rs0 = 0.f; rs1 = 0.f;
  };
  zeroAcc();

  // stage key-tile st into slot (K 16KB + V 16KB); 2 gld16 per thread
  auto stage = [&](int st, int slot) {
    u16* KbL = (u16*)(SM + slot * 32768);
    u16* VbL = (u16*)(SM + slot * 32768 + 16384);
    if (FAST) {
      const u16* ks = kbf + ((size_t)goff + st * 64) * DHEAD;
      const u16* vs = vtbf + (size_t)bh * DHEAD * T_SEQ + st * 64;
      { const int key = tid >> 4; const int db = (tid & 15) ^ (key & 7);
        gld_lds16(ks + (size_t)key * DHEAD + db * 8, KbL + w * 512); }
      { const int n = tid >> 3; const int kb = (tid & 7) ^ (n & 7);
        gld_lds16(vs + (size_t)n * T_SEQ + kb * 8, VbL + w * 512); }
    } else {
      const float ct = cg[goff + st * 64 + 63];
      const float* kp = kxg + hoff + (size_t)(st * 64) * DHEAD;
      const float* vp = vg + hoff + (size_t)(st * 64) * DHEAD;
      { const int key = tid >> 4; const int db = (tid & 15) ^ (key & 7);
        const float sc = __expf(ag[goff + st * 64 + key] - ct);
        const float4 x0 = *(const float4*)(kp + (size_t)key * DHEAD + db * 8);
        const float4 x1 = *(const float4*)(kp + (size_t)key * DHEAD + db * 8 + 4);
        u16x8 pk;
        pk[0] = f2bfu(x0.x * sc); pk[1] = f2bfu(x0.y * sc);
        pk[2] = f2bfu(x0.z * sc); pk[3] = f2bfu(x0.w * sc);
        pk[4] = f2bfu(x1.x * sc); pk[5] = f2bfu(x1.y * sc);
        pk[6] = f2bfu(x1.z * sc); pk[7] = f2bfu(x1.w * sc);
        *(u16x8*)(KbL + tid * 8) = pk; }
      { const int n = tid >> 3; const int kb = (tid & 7) ^ (n & 7);
        u16x8 pw;
#pragma unroll
        for (int rr = 0; rr < 8; ++rr)
          pw[rr] = f2bfu(vp[(size_t)(kb * 8 + rr) * DHEAD + n]);
        *(u16x8*)(VbL + tid * 8) = pw; }
    }
  };

  auto stagePair = [&](int s0, int lim, int pr) {
    if (s0 < lim)     stage(s0,     pr * 2);
    if (s0 + 1 < lim) stage(s0 + 1, pr * 2 + 1);
  };

  const int keyA = kg * 16 + l16;         // A-frag key row (QK)
  const int ksw  = l16 & 7;
  const int kbu  = kg * 2 + (quad >> 1);  // V unit base (PV)
  const int kofs = (quad & 1) * 4;

  auto computeStage = [&](int cqt, int st, int slot, float ccmax) {
    const u16* KbL = (const u16*)(SM + slot * 32768);
    const u16* VbL = (const u16*)(SM + slot * 32768 + 16384);

    // ---- S^T = K_hat Q^T ----
    f32x4 sa0 = (f32x4){0.f, 0.f, 0.f, 0.f};
    f32x4 sa1 = (f32x4){0.f, 0.f, 0.f, 0.f};
#pragma unroll
    for (int kc = 0; kc < 4; ++kc) {
      const bf16x8 kf = ldsFrag(KbL + keyA * 128 + (((kc * 4 + quad) ^ ksw) * 8));
      sa0 = __builtin_amdgcn_mfma_f32_16x16x32_bf16(kf, qf[kc],     sa0, 0, 0, 0);
      sa1 = __builtin_amdgcn_mfma_f32_16x16x32_bf16(kf, qf[4 + kc], sa1, 0, 0, 0);
    }

    const float etile = SCALE * __expf(cg[goff + st * 64 + 63] - ccmax);
    const bool diag = (st == cqt);
    const int kb0 = kg * 16 + quad * 4;

    s16x4 pfr0, pfr1;
    {
      float x0 = sa0[0] * etile, x1 = sa0[1] * etile;
      float x2 = sa0[2] * etile, x3 = sa0[3] * etile;
      if (diag) {
        const int qr = rh * 32 + l16;
        if (kb0 + 0 > qr) x0 = 0.f;
        if (kb0 + 1 > qr) x1 = 0.f;
        if (kb0 + 2 > qr) x2 = 0.f;
        if (kb0 + 3 > qr) x3 = 0.f;
      }
      rs0 += (x0 + x1) + (x2 + x3);
      pfr0 = __builtin_bit_cast(s16x4, (u32x2){packbf2(x0, x1), packbf2(x2, x3)});
    }
    {
      float x0 = sa1[0] * etile, x1 = sa1[1] * etile;
      float x2 = sa1[2] * etile, x3 = sa1[3] * etile;
      if (diag) {
        const int qr = rh * 32 + 16 + l16;
        if (kb0 + 0 > qr) x0 = 0.f;
        if (kb0 + 1 > qr) x1 = 0.f;
        if (kb0 + 2 > qr) x2 = 0.f;
        if (kb0 + 3 > qr) x3 = 0.f;
      }
      rs1 += (x0 + x1) + (x2 + x3);
      pfr1 = __builtin_bit_cast(s16x4, (u32x2){packbf2(x0, x1), packbf2(x2, x3)});
    }

    // ---- O^T += V^T P^T ----
#pragma unroll
    for (int mt = 0; mt < 8; ++mt) {
      const int vd = mt * 16 + l16;
      const s16x4 va = *(const s16x4*)(VbL + vd * 64 + ((kbu ^ (vd & 7)) * 8) + kofs);
      oa[mt][0] = mfma16x16x16bf16(va, pfr0, oa[mt][0]);
      oa[mt][1] = mfma16x16x16bf16(va, pfr1, oa[mt][1]);
    }
  };

  auto epilogue = [&](int eqt, float ecmax, int epair) {
    float* osh = (float*)(SM + epair * 65536);
    // rowsum: reduce over quads (keys), publish per (kg,sg) partials
    float x0 = rs0, x1 = rs1;
    x0 += __shfl_xor(x0, 16, 64); x0 += __shfl_xor(x0, 32, 64);
    x1 += __shfl_xor(x1, 16, 64); x1 += __shfl_xor(x1, 32, 64);
    if (lane < 16) {
      rsh[(w & 7) * 64 + rh * 32 + lane]      = x0;
      rsh[(w & 7) * 64 + rh * 32 + 16 + lane] = x1;
    }
    __syncthreads();
    if (w == 15) {
      const int row = lane;
      float tot = 0.f;
#pragma unroll
      for (int j = 0; j < 8; ++j) tot += rsh[j * 64 + row];
      const float nf = __expf(-(ecmax + fcg[goff + eqt * 64 + row]));
      ish[row] = 1.f / fmaxf(fabsf(tot), nf);
    }
    // 8-round partial-O combine over (kg,sg); rh halves write disjoint rows
    for (int r = 0; r < 8; ++r) {
      if ((w & 7) == r) {
        float iv0 = 0.f, iv1 = 0.f;
        if (r == 7) { iv0 = ish[rh * 32 + l16]; iv1 = ish[rh * 32 + 16 + l16]; }
#pragma unroll
        for (int mt = 0; mt < 8; ++mt)
#pragma unroll
          for (int nt = 0; nt < 2; ++nt)
#pragma unroll
            for (int rg = 0; rg < 4; ++rg) {
              const int row = rh * 32 + nt * 16 + l16;
              const int vd = mt * 16 + quad * 4 + rg;
              const int ad = row * 129 + vd;
              float vv = oa[mt][nt][rg];
              if (r > 0) vv += osh[ad];
              if (r == 7) vv *= (nt ? iv1 : iv0);
              osh[ad] = vv;
            }
      }
      __syncthreads();
    }
    // cooperative coalesced store
    const int col = tid & 31, r0 = tid >> 5;
#pragma unroll
    for (int i = 0; i < 2; ++i) {
      const int row = r0 + 32 * i;
      const float* lp = osh + row * 129 + col * 4;
      float4 vv; vv.x = lp[0]; vv.y = lp[1]; vv.z = lp[2]; vv.w = lp[3];
      *(float4*)(out + hoff + (size_t)(eqt * 64 + row) * DHEAD + col * 4) = vv;
    }
    __syncthreads();   // osh reads done before next phase's DMA reuses region
  };

  // -------- phase A then phase B: 17 uniform iterations --------
  int qt = qtA, n = qtA + 1;
  float cmax = cg[goff + qtA * 64 + 63];
  loadQ(qtA);
  stagePair(0, n, 0);
  __syncthreads();

  int pair = 0;
  for (int phase = 0; phase < 2; ++phase) {
    const int c = (n + 1) >> 1;
    for (int g = 0; g < c; ++g) {
      if (g + 1 < c)        stagePair(2 * (g + 1), n, pair ^ 1);
      else if (phase == 0)  stagePair(0, qtB + 1, pair ^ 1);
      const int st = 2 * g + sg;
      if (st < n) computeStage(qt, st, pair * 2 + sg, cmax);
      __syncthreads();
      pair ^= 1;
    }
    if (phase == 0) loadQ(qtB);          // hide Q-load latency under epilogue
    epilogue(qt, cmax, pair ^ 1);
    if (phase == 0) {
      zeroAcc();
      qt = qtB; n = qtB + 1;
      cmax = cg[goff + qtB * 64 + 63];
    }
  }
}

// ---------------------------------------------------------------------------
extern "C" void kernel_launch(void* const* d_in, const int* in_sizes, int n_in,
                              void* d_out, int out_size, void* d_ws, size_t ws_size,
                              hipStream_t stream) {
  const float* q  = (const float*)d_in[0];
  const float* k  = (const float*)d_in[1];
  const float* v  = (const float*)d_in[2];
  const float* ig = (const float*)d_in[3];
  const float* fg = (const float*)d_in[4];

  const size_t gate_bytes = (size_t)3 * NBH * T_SEQ * sizeof(float);
  const size_t kv_elems   = (size_t)NBH * T_SEQ * DHEAD;
  const bool fast = ws_size >= gate_bytes + 2 * kv_elems * sizeof(u16);

  float* a_ws  = (float*)d_ws;
  float* c_ws  = a_ws + NBH * T_SEQ;
  float* fc_ws = c_ws + NBH * T_SEQ;
  u16* kbf  = (u16*)((char*)d_ws + gate_bytes);
  u16* vtbf = kbf + kv_elems;

  gate_scan_kernel<<<dim3(NBH), dim3(1024), 0, stream>>>(ig, fg, a_ws, c_ws, fc_ws);
  if (fast) {
    cvt_kv_kernel<<<dim3(T_SEQ / 64, NBH), dim3(256), 0, stream>>>(
        k, v, a_ws, c_ws, kbf, vtbf);
    mlstm_fwd_kernel<true><<<dim3(256), dim3(1024), 0, stream>>>(
        q, k, v, kbf, vtbf, a_ws, c_ws, fc_ws, (float*)d_out);
  } else {
    mlstm_fwd_kernel<false><<<dim3(256), dim3(1024), 0, stream>>>(
        q, k, v, kbf, vtbf, a_ws, c_ws, fc_ws, (float*)d_out);
  }
}

// Round 3
// 146.779 us; speedup vs baseline: 1.3378x; 1.3378x over previous
//
#include <hip/hip_runtime.h>

#define T_SEQ 2048
#define DHEAD 128
#define NBH 16
#define SCALE 0.08838834764831845f

typedef unsigned short u16;
typedef unsigned int u32;
typedef u16 u16x4 __attribute__((ext_vector_type(4)));
typedef u16 u16x8 __attribute__((ext_vector_type(8)));
typedef u32 u32x2 __attribute__((ext_vector_type(2)));
typedef short s16x4 __attribute__((ext_vector_type(4)));
typedef __bf16 bf16x8 __attribute__((ext_vector_type(8)));
typedef float f32x4 __attribute__((ext_vector_type(4)));

#define SFENCE() __builtin_amdgcn_sched_barrier(0)

__device__ __forceinline__ u16 f2bfu(float x) {
  union { float f; unsigned u; } c; c.f = x;
  unsigned u = c.u;
  u = u + 0x7FFFu + ((u >> 16) & 1u);   // RNE
  return (u16)(u >> 16);
}

__device__ __forceinline__ bf16x8 ldsFrag(const u16* p) {
  u16x8 t = *(const u16x8*)p;
  return __builtin_bit_cast(bf16x8, t);
}

__device__ __forceinline__ f32x4 mfma16x16x16bf16(s16x4 a, s16x4 b, f32x4 c) {
#if __has_builtin(__builtin_amdgcn_mfma_f32_16x16x16bf16_1k)
  return __builtin_amdgcn_mfma_f32_16x16x16bf16_1k(a, b, c, 0, 0, 0);
#else
  asm("v_mfma_f32_16x16x16_bf16 %0, %1, %2, %0" : "+v"(c) : "v"(a), "v"(b));
  return c;
#endif
}

__device__ __forceinline__ void gld_lds16(const void* g, void* l) {
  __builtin_amdgcn_global_load_lds(
      (__attribute__((address_space(1))) const unsigned int*)g,
      (__attribute__((address_space(3))) unsigned int*)l, 16, 0, 0);
}

// ---------------------------------------------------------------------------
// Gate scan: fc=cumsum(logsigmoid(f)); a=i-fc; c=cummax(a).
// ---------------------------------------------------------------------------
__global__ __launch_bounds__(1024) void gate_scan_kernel(
    const float* __restrict__ ig, const float* __restrict__ fg,
    float* __restrict__ a_out, float* __restrict__ c_out,
    float* __restrict__ fc_out)
{
  const int bh = blockIdx.x, tid = threadIdx.x;
  const int w = tid >> 6, lane = tid & 63;
  const int base = bh * T_SEQ + tid * 2;
  __shared__ float wsum[16];
  __shared__ float wmax[16];

  const float x0 = fg[base], x1 = fg[base + 1];
  const float ls0 = fminf(x0, 0.f) - log1pf(expf(-fabsf(x0)));
  const float ls1 = fminf(x1, 0.f) - log1pf(expf(-fabsf(x1)));
  const float s = ls0 + ls1;

  float sc = s;
#pragma unroll
  for (int off = 1; off < 64; off <<= 1) {
    const float t = __shfl_up(sc, off, 64);
    if (lane >= off) sc += t;
  }
  if (lane == 63) wsum[w] = sc;
  __syncthreads();
  float wo = 0.f;
#pragma unroll
  for (int i = 0; i < 15; ++i) if (i < w) wo += wsum[i];
  const float excl = wo + (sc - s);
  const float fc0 = excl + ls0;
  const float fc1 = excl + ls0 + ls1;
  fc_out[base] = fc0; fc_out[base + 1] = fc1;
  const float a0 = ig[base] - fc0;
  const float a1 = ig[base + 1] - fc1;
  a_out[base] = a0; a_out[base + 1] = a1;

  const float m = fmaxf(a0, a1);
  float mc = m;
#pragma unroll
  for (int off = 1; off < 64; off <<= 1) {
    const float t = __shfl_up(mc, off, 64);
    if (lane >= off) mc = fmaxf(mc, t);
  }
  if (lane == 63) wmax[w] = mc;
  __syncthreads();
  float wmo = -INFINITY;
#pragma unroll
  for (int i = 0; i < 15; ++i) if (i < w) wmo = fmaxf(wmo, wmax[i]);
  const float prev = __shfl_up(mc, 1, 64);
  float exclm = (lane > 0) ? prev : -INFINITY;
  exclm = fmaxf(exclm, wmo);
  c_out[base] = fmaxf(exclm, a0);
  c_out[base + 1] = fmaxf(exclm, m);
}

// ---------------------------------------------------------------------------
// Fused pre-pass: K_hat = K*exp(a-c_end) fp32->bf16; V -> bf16 Vt transposed.
// ---------------------------------------------------------------------------
__global__ __launch_bounds__(256) void cvt_kv_kernel(
    const float* __restrict__ kk, const float* __restrict__ v,
    const float* __restrict__ ag, const float* __restrict__ cg,
    u16* __restrict__ kbf, u16* __restrict__ vt)
{
  const int bh = blockIdx.y, kt = blockIdx.x, tid = threadIdx.x;
  // ---- K part ----
  {
    const int r = tid >> 2;                 // 0..63
    const int c0 = (tid & 3) * 32;
    const int row = kt * 64 + r;
    const float sc = __expf(ag[bh * T_SEQ + row] - cg[bh * T_SEQ + (row | 63)]);
    const float* sp = kk + ((size_t)bh * T_SEQ + row) * DHEAD + c0;
    u16* dp = kbf + ((size_t)bh * T_SEQ + row) * DHEAD + c0;
#pragma unroll
    for (int j = 0; j < 8; ++j) {
      const float4 x = *(const float4*)(sp + j * 4);
      u16x4 pq;
      pq[0] = f2bfu(x.x * sc); pq[1] = f2bfu(x.y * sc);
      pq[2] = f2bfu(x.z * sc); pq[3] = f2bfu(x.w * sc);
      *(u16x4*)(dp + j * 4) = pq;
    }
  }
  // ---- V transpose part ----
  __shared__ __align__(16) u16 L[128 * 72];
  const int n0 = (tid & 31) * 4, k0 = (tid >> 5) * 8;
  const float* vp = v + ((size_t)bh * T_SEQ + kt * 64 + k0) * DHEAD + n0;
  u16 tv[4][8];
#pragma unroll
  for (int rr = 0; rr < 8; ++rr) {
    const float4 x = *(const float4*)(vp + rr * DHEAD);
    tv[0][rr] = f2bfu(x.x); tv[1][rr] = f2bfu(x.y);
    tv[2][rr] = f2bfu(x.z); tv[3][rr] = f2bfu(x.w);
  }
#pragma unroll
  for (int j = 0; j < 4; ++j) {
    u16x8 pq;
#pragma unroll
    for (int rr = 0; rr < 8; ++rr) pq[rr] = tv[j][rr];
    *(u16x8*)(&L[(n0 + j) * 72 + k0]) = pq;
  }
  __syncthreads();
  const int row = tid >> 1, s0 = (tid & 1) * 32;
  u16* op = vt + ((size_t)bh * DHEAD + row) * T_SEQ + kt * 64 + s0;
#pragma unroll
  for (int i = 0; i < 4; ++i)
    *(u16x8*)(op + i * 8) = *(const u16x8*)(&L[row * 72 + s0 + i * 8]);
}

// ---------------------------------------------------------------------------
// Main flash mLSTM.  256 blocks x 1024 thr (16 waves).
// UNIFORM 33-stage sequence (tile A=31-p stages 0..31-p, then tile B=p
// stages 0..p). Wave = kg(4 key-groups of 16) x rq(4 row-quarters of 16).
// COUNTED-VMCNT 3-slot pipeline (T3/T4): per iter
//   s_waitcnt vmcnt(2)  -> stage(s) landed, stage(s+1) stays in flight
//   raw s_barrier       -> no vmcnt drain (unlike __syncthreads)
//   issue stage(s+2)    -> into slot freed by stage(s-1)
//   compute stage(s)
// Epilogue uses lgkm-only barriers so B loads stay in flight across epi A.
// Register budget: oa[8](32 AGPR) + qf[4](16) + temps  << 128/wave cap.
// ---------------------------------------------------------------------------
template <bool FAST>
__global__ __launch_bounds__(1024, 4) void mlstm_fwd_kernel(
    const float* __restrict__ qg, const float* __restrict__ kxg,
    const float* __restrict__ vg,
    const u16* __restrict__ kbf, const u16* __restrict__ vtbf,
    const float* __restrict__ ag, const float* __restrict__ cg,
    const float* __restrict__ fcg, float* __restrict__ out)
{
  const int bx = (int)blockIdx.x;
  const int bh = bx & 15, p = bx >> 4;
  const int tid = (int)threadIdx.x;
  const int w = tid >> 6, lane = tid & 63;
  const int quad = lane >> 4, l16 = lane & 15;
  const int kg = w & 3, rq = w >> 2;

  const int qtA = 31 - p, qtB = p;
  const int nA = qtA + 1;                 // nA + (qtB+1) == 33 for all p

  // LDS: 3 staging slots x 32KB (K 16K + V 16K) @0..98304;
  //      osh 64x132 f32 @98304 (33792B); rsh 4x64 f32 @132096.
  __shared__ __align__(16) unsigned char SM[133120];
  u16* Kst = (u16*)SM;
  float* osh = (float*)(SM + 98304);
  float* rsh = (float*)(SM + 132096);

  const size_t hoff = (size_t)bh * T_SEQ * DHEAD;
  const int goff = bh * T_SEQ;

  // raw barrier with lgkm-only wait (keeps vmcnt pipeline alive)
  auto barL = [&]() {
    asm volatile("s_waitcnt lgkmcnt(0)" ::: "memory");
    SFENCE();
    __builtin_amdgcn_s_barrier();
    SFENCE();
  };

  // Q -> B-frags qf[kc]: B[k=quad*8+j][n=l16], row = qt*64 + rq*16 + l16
  bf16x8 qf[4];
  auto loadQ = [&](int lqt) {
    const float* qp = qg + hoff + (size_t)(lqt * 64 + rq * 16 + l16) * DHEAD + quad * 8;
#pragma unroll
    for (int kc = 0; kc < 4; ++kc) {
      const float4 x0 = *(const float4*)(qp + kc * 32);
      const float4 x1 = *(const float4*)(qp + kc * 32 + 4);
      u16x8 t;
      t[0] = f2bfu(x0.x); t[1] = f2bfu(x0.y); t[2] = f2bfu(x0.z); t[3] = f2bfu(x0.w);
      t[4] = f2bfu(x1.x); t[5] = f2bfu(x1.y); t[6] = f2bfu(x1.z); t[7] = f2bfu(x1.w);
      qf[kc] = __builtin_bit_cast(bf16x8, t);
    }
  };

  f32x4 oa[8];                           // O^T partial: 8 vd-tiles x 16 rows
  float rsacc;
  auto zeroAcc = [&]() {
#pragma unroll
    for (int mt = 0; mt < 8; ++mt) oa[mt] = (f32x4){0.f, 0.f, 0.f, 0.f};
    rsacc = 0.f;
  };
  zeroAcc();

  // ---- loop-invariant staging addresses (FAST path) ----
  const int skey = tid >> 4, sdb = (tid & 15) ^ (skey & 7);
  const u16* ksBase = kbf + (size_t)goff * DHEAD + (size_t)skey * DHEAD + sdb * 8;
  const int svn = tid >> 3, svk = (tid & 7) ^ (svn & 7);
  const u16* vsBase = vtbf + (size_t)bh * DHEAD * T_SEQ + (size_t)svn * T_SEQ + svk * 8;

  // stage key-tile st (phase-local) into slot; 2 vmem ops per thread
  auto stage = [&](int st, int slot) {
    u16* KbL = Kst + slot * 16384;
    u16* VbL = Kst + slot * 16384 + 8192;
    if (FAST) {
      gld_lds16(ksBase + (size_t)st * 64 * DHEAD, KbL + w * 512);
      gld_lds16(vsBase + st * 64, VbL + w * 512);
    } else {
      const float ct = cg[goff + st * 64 + 63];
      const float* kp = kxg + hoff + (size_t)(st * 64) * DHEAD;
      const float* vp = vg + hoff + (size_t)(st * 64) * DHEAD;
      { const float scv = __expf(ag[goff + st * 64 + skey] - ct);
        const float4 x0 = *(const float4*)(kp + (size_t)skey * DHEAD + sdb * 8);
        const float4 x1 = *(const float4*)(kp + (size_t)skey * DHEAD + sdb * 8 + 4);
        u16x8 pk;
        pk[0] = f2bfu(x0.x * scv); pk[1] = f2bfu(x0.y * scv);
        pk[2] = f2bfu(x0.z * scv); pk[3] = f2bfu(x0.w * scv);
        pk[4] = f2bfu(x1.x * scv); pk[5] = f2bfu(x1.y * scv);
        pk[6] = f2bfu(x1.z * scv); pk[7] = f2bfu(x1.w * scv);
        *(u16x8*)(KbL + tid * 8) = pk; }
      { u16x8 pw;
#pragma unroll
        for (int rr = 0; rr < 8; ++rr)
          pw[rr] = f2bfu(vp[(size_t)(svk * 8 + rr) * DHEAD + svn]);
        *(u16x8*)(VbL + tid * 8) = pw; }
    }
  };
  auto stageSeq = [&](int seq, int slot) {
    stage(seq < nA ? seq : seq - nA, slot);
  };

  const int keyA = kg * 16 + l16;         // A-frag key row (QK)
  const int ksw  = l16 & 7;
  const int kbu  = kg * 2 + (quad >> 1);  // V unit base (PV)
  // vd&7 == l16&7 for all mt -> V swizzle is mt-invariant:
  const int vbase = l16 * 64 + ((kbu ^ (l16 & 7)) * 8) + (quad & 1) * 4;

  auto computeStage = [&](int cqt, int st, int slot, float ccmax) {
    const u16* KbL = Kst + slot * 16384;
    const u16* VbL = Kst + slot * 16384 + 8192;

    // ---- S^T = K_hat Q^T ----
    f32x4 sa = (f32x4){0.f, 0.f, 0.f, 0.f};
#pragma unroll
    for (int kc = 0; kc < 4; ++kc) {
      const bf16x8 kf = ldsFrag(KbL + keyA * 128 + (((kc * 4 + quad) ^ ksw) * 8));
      sa = __builtin_amdgcn_mfma_f32_16x16x32_bf16(kf, qf[kc], sa, 0, 0, 0);
    }

    const float etile = SCALE * __expf(cg[goff + st * 64 + 63] - ccmax);
    float x0 = sa[0] * etile, x1 = sa[1] * etile;
    float x2 = sa[2] * etile, x3 = sa[3] * etile;
    if (st == cqt) {
      const int qr = rq * 16 + l16, kb0 = kg * 16 + quad * 4;
      if (kb0 + 0 > qr) x0 = 0.f;
      if (kb0 + 1 > qr) x1 = 0.f;
      if (kb0 + 2 > qr) x2 = 0.f;
      if (kb0 + 3 > qr) x3 = 0.f;
    }
    rsacc += (x0 + x1) + (x2 + x3);
    u32 plo, phi;
    asm("v_cvt_pk_bf16_f32 %0, %1, %2" : "=v"(plo) : "v"(x0), "v"(x1));
    asm("v_cvt_pk_bf16_f32 %0, %1, %2" : "=v"(phi) : "v"(x2), "v"(x3));
    const s16x4 pfr = __builtin_bit_cast(s16x4, (u32x2){plo, phi});

    // ---- O^T += V^T P^T ----  (addresses: base + mt*1024 -> offset imms)
#pragma unroll
    for (int mt = 0; mt < 8; ++mt) {
      const s16x4 va = *(const s16x4*)(VbL + vbase + mt * 1024);
      oa[mt] = mfma16x16x16bf16(va, pfr, oa[mt]);
    }
  };

  auto epilogue = [&](int eqt, float ecmax) {
    // rowsum: reduce across quads (keys), combine key-groups via LDS
    float x = rsacc;
    x += __shfl_xor(x, 16, 64);
    x += __shfl_xor(x, 32, 64);
    if (lane < 16) rsh[kg * 64 + rq * 16 + lane] = x;
    barL();
    float inv = 0.f;
    if (kg == 3) {
      const int row = rq * 16 + l16;
      const float tot = rsh[row] + rsh[64 + row] + rsh[128 + row] + rsh[192 + row];
      const float nf = __expf(-(ecmax + fcg[goff + eqt * 64 + row]));
      inv = 1.f / fmaxf(fabsf(tot), nf);
    }
    // 4-round partial-O combine over kg (float4, stride 132)
    for (int r = 0; r < 4; ++r) {
      if (kg == r) {
        const int row = rq * 16 + l16;
#pragma unroll
        for (int mt = 0; mt < 8; ++mt) {
          float* ap = osh + row * 132 + mt * 16 + quad * 4;
          f32x4 vv = oa[mt];
          if (r > 0) vv = vv + *(const f32x4*)ap;
          if (r == 3) vv = vv * inv;
          *(f32x4*)ap = vv;
        }
      }
      barL();
    }
    // cooperative coalesced store
    const int col = tid & 31, r0 = tid >> 5;
#pragma unroll
    for (int i = 0; i < 2; ++i) {
      const int row = r0 + 32 * i;
      const f32x4 vv = *(const f32x4*)(osh + row * 132 + col * 4);
      *(f32x4*)(out + hoff + (size_t)(eqt * 64 + row) * DHEAD + col * 4) = vv;
    }
  };

  // -------- prologue --------
  int qt = qtA;
  float cmax = cg[goff + qtA * 64 + 63];
  loadQ(qtA);
  stageSeq(0, 0);
  stageSeq(1, 1);

  // -------- 33 uniform pipelined iterations --------
  int sl = 0;
  for (int s = 0; s < 33; ++s) {
    if (s < 32) { asm volatile("s_waitcnt vmcnt(2)" ::: "memory"); }
    else        { asm volatile("s_waitcnt vmcnt(0)" ::: "memory"); }
    if (!FAST)  { asm volatile("s_waitcnt lgkmcnt(0)" ::: "memory"); }
    SFENCE();
    __builtin_amdgcn_s_barrier();
    SFENCE();

    if (s + 2 < 33) {
      const int sl2 = (sl >= 1) ? sl - 1 : 2;   // (sl+2)%3
      stageSeq(s + 2, sl2);
    }
    const int stq = (s < nA) ? s : s - nA;
    computeStage(qt, stq, sl, cmax);

    if (s == nA - 1) {
      loadQ(qtB);                 // hide under epilogue (costs one pipe bubble)
      epilogue(qtA, cmax);
      zeroAcc();
      qt = qtB;
      cmax = cg[goff + qtB * 64 + 63];
    }
    sl = (sl == 2) ? 0 : sl + 1;
  }
  epilogue(qtB, cmax);
}

// ---------------------------------------------------------------------------
extern "C" void kernel_launch(void* const* d_in, const int* in_sizes, int n_in,
                              void* d_out, int out_size, void* d_ws, size_t ws_size,
                              hipStream_t stream) {
  const float* q  = (const float*)d_in[0];
  const float* k  = (const float*)d_in[1];
  const float* v  = (const float*)d_in[2];
  const float* ig = (const float*)d_in[3];
  const float* fg = (const float*)d_in[4];

  const size_t gate_bytes = (size_t)3 * NBH * T_SEQ * sizeof(float);
  const size_t kv_elems   = (size_t)NBH * T_SEQ * DHEAD;
  const bool fast = ws_size >= gate_bytes + 2 * kv_elems * sizeof(u16);

  float* a_ws  = (float*)d_ws;
  float* c_ws  = a_ws + NBH * T_SEQ;
  float* fc_ws = c_ws + NBH * T_SEQ;
  u16* kbf  = (u16*)((char*)d_ws + gate_bytes);
  u16* vtbf = kbf + kv_elems;

  gate_scan_kernel<<<dim3(NBH), dim3(1024), 0, stream>>>(ig, fg, a_ws, c_ws, fc_ws);
  if (fast) {
    cvt_kv_kernel<<<dim3(T_SEQ / 64, NBH), dim3(256), 0, stream>>>(
        k, v, a_ws, c_ws, kbf, vtbf);
    mlstm_fwd_kernel<true><<<dim3(256), dim3(1024), 0, stream>>>(
        q, k, v, kbf, vtbf, a_ws, c_ws, fc_ws, (float*)d_out);
  } else {
    mlstm_fwd_kernel<false><<<dim3(256), dim3(1024), 0, stream>>>(
        q, k, v, kbf, vtbf, a_ws, c_ws, fc_ws, (float*)d_out);
  }
}